// Round 1
// baseline (417.989 us; speedup 1.0000x reference)
//
#include <hip/hip_runtime.h>
#include <hip/hip_bf16.h>
#include <stdint.h>
#include <stddef.h>

// Problem constants
#define B_ 32
#define N_ 1024
#define C_ 768
#define H_ 12
#define D_ 64
#define M_ (B_*N_)     // 32768 rows
#define TC_ (3*C_)     // 2304 qkv cols

typedef __bf16 bf16_t;
typedef __attribute__((ext_vector_type(8))) __bf16 bf16x8;
typedef __attribute__((ext_vector_type(4))) __bf16 bf16x4;
typedef __attribute__((ext_vector_type(4))) float  f32x4;

#define MFMA16(a,b,c) __builtin_amdgcn_mfma_f32_16x16x32_bf16(a,b,c,0,0,0)

__device__ __forceinline__ void lds_load16(const void* g, void* l) {
  __builtin_amdgcn_global_load_lds(
      (const __attribute__((address_space(1))) void*)g,
      (__attribute__((address_space(3))) void*)l, 16, 0, 0);
}

// ---------------------------------------------------------------- converts
__global__ void cvt_bf16(const float* __restrict__ in, bf16_t* __restrict__ out, int n) {
  int i = (blockIdx.x * 256 + threadIdx.x) * 8;
  if (i >= n) return;
  const float4 a = *(const float4*)(in + i);
  const float4 b = *(const float4*)(in + i + 4);
  bf16x8 r;
  r[0]=(bf16_t)a.x; r[1]=(bf16_t)a.y; r[2]=(bf16_t)a.z; r[3]=(bf16_t)a.w;
  r[4]=(bf16_t)b.x; r[5]=(bf16_t)b.y; r[6]=(bf16_t)b.z; r[7]=(bf16_t)b.w;
  *(bf16x8*)(out + i) = r;
}

// out[c][r] = bf16(in[r][c]); grid (Cc/32, R/32), 256 threads
__global__ void transpose_cvt(const float* __restrict__ in, bf16_t* __restrict__ out,
                              int R, int Cc) {
  __shared__ float t[32][33];
  const int c0 = blockIdx.x * 32, r0 = blockIdx.y * 32;
  const int tx = threadIdx.x & 31, ty = threadIdx.x >> 5;  // ty 0..7
  #pragma unroll
  for (int k = 0; k < 4; ++k)
    t[ty + k*8][tx] = in[(size_t)(r0 + ty + k*8)*Cc + c0 + tx];
  __syncthreads();
  #pragma unroll
  for (int k = 0; k < 4; ++k)
    out[(size_t)(c0 + ty + k*8)*R + r0 + tx] = (bf16_t)t[tx][ty + k*8];
}

// ---------------------------------------------------------------- GEMM (A row-major MxK, BT row-major NxK)
// MODE 0: Cout = A@B + bias (fp32, stride Ndim)
// MODE 1: qkv scatter with hi/lo split k/v
// MODE 2: qkv scatter, hi only
template<int MODE>
__global__ __launch_bounds__(256, 2)
void gemm_bt(const bf16_t* __restrict__ A, const bf16_t* __restrict__ BT,
             const float* __restrict__ bias, float* __restrict__ Cout,
             bf16_t* __restrict__ qh,
             bf16_t* __restrict__ kthi, bf16_t* __restrict__ ktlo,
             bf16_t* __restrict__ vthi, bf16_t* __restrict__ vtlo,
             int K, int Ndim)
{
  __shared__ bf16_t As[128*32];
  __shared__ bf16_t Bs[128*32];
  const int tid  = threadIdx.x;
  const int wave = tid >> 6;
  const int lane = tid & 63;
  const int rowBase = blockIdx.y * 128;
  const int colBase = blockIdx.x * 128;
  const int wr = (wave >> 1) * 64;
  const int wc = (wave &  1) * 64;
  const int fr = lane & 15;
  const int fo = (lane >> 4) * 8;
  const int e  = tid * 8;
  const int r0 = e >> 5;     // tile row within [128][32]
  const int c0 = e & 31;

  const bf16_t* Ap = A  + (size_t)(rowBase + r0) * K + c0;
  const bf16_t* Bp = BT + (size_t)(colBase + r0) * K + c0;

  f32x4 acc[4][4] = {{0.f,0.f,0.f,0.f}};

  for (int k0 = 0; k0 < K; k0 += 32) {
    lds_load16(Ap + k0,                 &As[wave*512]);
    lds_load16(Ap + (size_t)64*K + k0,  &As[2048 + wave*512]);
    lds_load16(Bp + k0,                 &Bs[wave*512]);
    lds_load16(Bp + (size_t)64*K + k0,  &Bs[2048 + wave*512]);
    __syncthreads();
    bf16x8 af[4], bfv[4];
    #pragma unroll
    for (int m = 0; m < 4; ++m) af[m]  = *(const bf16x8*)&As[(wr + m*16 + fr)*32 + fo];
    #pragma unroll
    for (int n = 0; n < 4; ++n) bfv[n] = *(const bf16x8*)&Bs[(wc + n*16 + fr)*32 + fo];
    #pragma unroll
    for (int m = 0; m < 4; ++m)
      #pragma unroll
      for (int n = 0; n < 4; ++n)
        acc[m][n] = MFMA16(af[m], bfv[n], acc[m][n]);
    __syncthreads();
  }

  if (MODE == 0) {
    #pragma unroll
    for (int n = 0; n < 4; ++n) {
      const int gc = colBase + wc + n*16 + fr;
      const float bb = bias[gc];
      #pragma unroll
      for (int m = 0; m < 4; ++m) {
        const int gr = rowBase + wr + m*16 + ((lane >> 4) << 2);
        #pragma unroll
        for (int j = 0; j < 4; ++j)
          Cout[(size_t)(gr + j)*Ndim + gc] = acc[m][n][j] + bb;
      }
    }
  } else {
    const int s = colBase / C_;   // 0=q 1=k 2=v, uniform per block (768 % 128 == 0)
    #pragma unroll
    for (int m = 0; m < 4; ++m) {
      const int gr = rowBase + wr + m*16 + ((lane >> 4) << 2);
      const int b  = gr >> 10;
      const int nn = gr & (N_ - 1);
      #pragma unroll
      for (int n = 0; n < 4; ++n) {
        const int gc  = colBase + wc + n*16 + fr;
        const float bb = bias[gc];
        const int rem = gc - s*C_;
        const int h = rem >> 6;
        const int d = rem & 63;
        const size_t bh = (size_t)b*H_ + h;
        const float v0 = acc[m][n][0] + bb, v1 = acc[m][n][1] + bb;
        const float v2 = acc[m][n][2] + bb, v3 = acc[m][n][3] + bb;
        if (s == 0) {
          bf16_t* q = qh + (bh*N_ + nn)*D_ + d;
          q[0]    = (bf16_t)v0;
          q[D_]   = (bf16_t)v1;
          q[2*D_] = (bf16_t)v2;
          q[3*D_] = (bf16_t)v3;
        } else {
          bf16_t* hi = (s == 1 ? kthi : vthi) + (bh*D_ + d)*N_ + nn;
          bf16x4 hv;
          hv[0]=(bf16_t)v0; hv[1]=(bf16_t)v1; hv[2]=(bf16_t)v2; hv[3]=(bf16_t)v3;
          *(bf16x4*)hi = hv;
          if (MODE == 1) {
            bf16_t* lo = (s == 1 ? ktlo : vtlo) + (bh*D_ + d)*N_ + nn;
            bf16x4 lv;
            lv[0]=(bf16_t)(v0 - (float)hv[0]); lv[1]=(bf16_t)(v1 - (float)hv[1]);
            lv[2]=(bf16_t)(v2 - (float)hv[2]); lv[3]=(bf16_t)(v3 - (float)hv[3]);
            *(bf16x4*)lo = lv;
          }
        }
      }
    }
  }
}

// ---------------------------------------------------------------- stage 2: logits + softmax
// attn[bh][d][e] = softmax_e( sum_n kt[d][n]*vt[e][n] / 8 ), kt/vt are (D,N) hi/lo bf16
template<bool SPLIT>
__global__ __launch_bounds__(256, 2)
void attn_softmax_k(const bf16_t* __restrict__ kthi, const bf16_t* __restrict__ ktlo,
                    const bf16_t* __restrict__ vthi, const bf16_t* __restrict__ vtlo,
                    bf16_t* __restrict__ attn)
{
  __shared__ float tile[64][65];
  const int bh = blockIdx.x;
  const int tid = threadIdx.x, wave = tid >> 6, lane = tid & 63;
  const int fr = lane & 15, fo = (lane >> 4) * 8;
  const size_t base = (size_t)bh * D_ * N_;
  f32x4 acc[4][4] = {{0.f,0.f,0.f,0.f}};
  const int k0lo = wave * 256;   // split-K across 4 waves
  #pragma unroll 1
  for (int k0 = k0lo; k0 < k0lo + 256; k0 += 32) {
    bf16x8 ah[4], bhv[4], al[4], bl[4];
    #pragma unroll
    for (int m = 0; m < 4; ++m) {
      const size_t o = base + (size_t)(m*16 + fr)*N_ + k0 + fo;
      ah[m] = *(const bf16x8*)&kthi[o];
      if (SPLIT) al[m] = *(const bf16x8*)&ktlo[o];
    }
    #pragma unroll
    for (int n = 0; n < 4; ++n) {
      const size_t o = base + (size_t)(n*16 + fr)*N_ + k0 + fo;
      bhv[n] = *(const bf16x8*)&vthi[o];
      if (SPLIT) bl[n] = *(const bf16x8*)&vtlo[o];
    }
    #pragma unroll
    for (int m = 0; m < 4; ++m)
      #pragma unroll
      for (int n = 0; n < 4; ++n) {
        acc[m][n] = MFMA16(ah[m], bhv[n], acc[m][n]);
        if (SPLIT) {
          acc[m][n] = MFMA16(ah[m], bl[n], acc[m][n]);
          acc[m][n] = MFMA16(al[m], bhv[n], acc[m][n]);
        }
      }
  }
  // cross-wave reduce into LDS
  for (int w = 0; w < 4; ++w) {
    if (wave == w) {
      #pragma unroll
      for (int m = 0; m < 4; ++m)
        #pragma unroll
        for (int n = 0; n < 4; ++n) {
          const int row = m*16 + ((lane >> 4) << 2);
          const int col = n*16 + fr;
          #pragma unroll
          for (int j = 0; j < 4; ++j) {
            if (w == 0) tile[row+j][col]  = acc[m][n][j];
            else        tile[row+j][col] += acc[m][n][j];
          }
        }
    }
    __syncthreads();
  }
  // row softmax (scale 1/8), one thread per row
  if (tid < 64) {
    float mx = -3.0e38f;
    #pragma unroll
    for (int c = 0; c < 64; ++c) mx = fmaxf(mx, tile[tid][c]);
    mx *= 0.125f;
    float ssum = 0.f;
    #pragma unroll
    for (int c = 0; c < 64; ++c) {
      const float ev = __expf(tile[tid][c]*0.125f - mx);
      tile[tid][c] = ev;
      ssum += ev;
    }
    const float inv = 1.0f / ssum;
    bf16_t* ao = attn + (size_t)bh * D_ * D_ + tid * D_;
    #pragma unroll
    for (int c = 0; c < 64; ++c) ao[c] = (bf16_t)(tile[tid][c] * inv);
  }
}

// ---------------------------------------------------------------- stage 3: out2 = Q @ attn^T, merge heads
// y2[b][n][h*64+d] = sum_e attn[d][e] * q[n][e]
__global__ __launch_bounds__(256, 2)
void attn_apply(const bf16_t* __restrict__ qh, const bf16_t* __restrict__ attn,
                bf16_t* __restrict__ y2)
{
  const int bh = blockIdx.y;
  const int b = bh / H_, h = bh - b*H_;
  const int tid = threadIdx.x, wave = tid >> 6, lane = tid & 63;
  const int fr = lane & 15, fo = (lane >> 4) * 8;
  const int n0 = blockIdx.x * 256 + wave * 64;
  const bf16_t* qb = qh   + (size_t)bh * N_ * D_;
  const bf16_t* ab = attn + (size_t)bh * D_ * D_;
  f32x4 acc[4][4] = {{0.f,0.f,0.f,0.f}};
  #pragma unroll
  for (int k0 = 0; k0 < 64; k0 += 32) {
    bf16x8 af[4], bfv[4];
    #pragma unroll
    for (int m = 0; m < 4; ++m)
      af[m] = *(const bf16x8*)&qb[(size_t)(n0 + m*16 + fr)*D_ + k0 + fo];
    #pragma unroll
    for (int n = 0; n < 4; ++n)
      bfv[n] = *(const bf16x8*)&ab[(n*16 + fr)*D_ + k0 + fo];
    #pragma unroll
    for (int m = 0; m < 4; ++m)
      #pragma unroll
      for (int n = 0; n < 4; ++n)
        acc[m][n] = MFMA16(af[m], bfv[n], acc[m][n]);
  }
  #pragma unroll
  for (int m = 0; m < 4; ++m) {
    const int nr = n0 + m*16 + ((lane >> 4) << 2);
    #pragma unroll
    for (int n = 0; n < 4; ++n) {
      const int d = n*16 + fr;
      #pragma unroll
      for (int j = 0; j < 4; ++j)
        y2[(size_t)(b*N_ + nr + j)*C_ + h*D_ + d] = (bf16_t)acc[m][n][j];
    }
  }
}

// ---------------------------------------------------------------- launcher
extern "C" void kernel_launch(void* const* d_in, const int* in_sizes, int n_in,
                              void* d_out, int out_size, void* d_ws, size_t ws_size,
                              hipStream_t stream)
{
  (void)in_sizes; (void)n_in; (void)out_size;
  const float* x     = (const float*)d_in[0];
  const float* w_qkv = (const float*)d_in[1];
  const float* b_qkv = (const float*)d_in[2];
  const float* w_out = (const float*)d_in[3];
  const float* b_out = (const float*)d_in[4];
  float* out = (float*)d_out;

  const size_t sz_xb   = (size_t)M_*C_*2;        // 50.3 MB
  const size_t sz_wq   = (size_t)TC_*C_*2;       //  3.5 MB
  const size_t sz_wo   = (size_t)C_*C_*2;        //  1.2 MB
  const size_t sz_qh   = (size_t)B_*H_*N_*D_*2;  // 50.3 MB
  const size_t sz_kv   = (size_t)B_*H_*D_*N_*2;  // 50.3 MB each
  const size_t sz_attn = (size_t)B_*H_*D_*D_*2;  //  3.1 MB

  char* p = (char*)d_ws;
  bf16_t* xb    = (bf16_t*)p; p += sz_xb;
  bf16_t* wqkvT = (bf16_t*)p; p += sz_wq;
  bf16_t* woutT = (bf16_t*)p; p += sz_wo;
  bf16_t* qh    = (bf16_t*)p; p += sz_qh;
  bf16_t* kthi  = (bf16_t*)p; p += sz_kv;
  bf16_t* vthi  = (bf16_t*)p; p += sz_kv;
  bf16_t* attn  = (bf16_t*)p; p += sz_attn;
  const size_t base_need = (size_t)(p - (char*)d_ws);
  bf16_t* ktlo  = (bf16_t*)p;
  bf16_t* vtlo  = (bf16_t*)(p + sz_kv);
  const size_t split_need = base_need + 2*sz_kv;
  bf16_t* y2 = xb;   // xb is dead after GEMM1; reuse for merged attention output

  if (ws_size < base_need) return;   // leaves poison -> distinctive failure
  const bool split = (ws_size >= split_need);

  cvt_bf16<<<dim3((M_*C_)/2048), 256, 0, stream>>>(x, xb, M_*C_);
  transpose_cvt<<<dim3(TC_/32, C_/32), 256, 0, stream>>>(w_qkv, wqkvT, C_, TC_);
  transpose_cvt<<<dim3(C_/32,  C_/32), 256, 0, stream>>>(w_out, woutT, C_, C_);

  if (split) {
    gemm_bt<1><<<dim3(TC_/128, M_/128), 256, 0, stream>>>(
        xb, wqkvT, b_qkv, nullptr, qh, kthi, ktlo, vthi, vtlo, C_, 0);
    attn_softmax_k<true><<<dim3(B_*H_), 256, 0, stream>>>(kthi, ktlo, vthi, vtlo, attn);
  } else {
    gemm_bt<2><<<dim3(TC_/128, M_/128), 256, 0, stream>>>(
        xb, wqkvT, b_qkv, nullptr, qh, kthi, nullptr, vthi, nullptr, C_, 0);
    attn_softmax_k<false><<<dim3(B_*H_), 256, 0, stream>>>(kthi, nullptr, vthi, nullptr, attn);
  }

  attn_apply<<<dim3(N_/256, B_*H_), 256, 0, stream>>>(qh, attn, y2);

  gemm_bt<0><<<dim3(C_/128, M_/128), 256, 0, stream>>>(
      y2, woutT, b_out, out, nullptr, nullptr, nullptr, nullptr, nullptr, C_, C_);
}

// Round 2
// 300.868 us; speedup vs baseline: 1.3893x; 1.3893x over previous
//
#include <hip/hip_runtime.h>
#include <hip/hip_bf16.h>
#include <stdint.h>
#include <stddef.h>

// Problem constants
#define B_ 32
#define N_ 1024
#define C_ 768
#define H_ 12
#define D_ 64
#define M_ (B_*N_)     // 32768 rows
#define TC_ (3*C_)     // 2304 qkv cols

typedef __bf16 bf16_t;
typedef __attribute__((ext_vector_type(8))) __bf16 bf16x8;
typedef __attribute__((ext_vector_type(4))) __bf16 bf16x4;
typedef __attribute__((ext_vector_type(4))) float  f32x4;

#define MFMA16(a,b,c) __builtin_amdgcn_mfma_f32_16x16x32_bf16(a,b,c,0,0,0)

__device__ __forceinline__ void lds_load16(const void* g, void* l) {
  __builtin_amdgcn_global_load_lds(
      (const __attribute__((address_space(1))) void*)g,
      (__attribute__((address_space(3))) void*)l, 16, 0, 0);
}

// ---------------------------------------------------------------- converts
__global__ void cvt_bf16(const float* __restrict__ in, bf16_t* __restrict__ out, int n) {
  int i = (blockIdx.x * 256 + threadIdx.x) * 8;
  if (i >= n) return;
  const float4 a = *(const float4*)(in + i);
  const float4 b = *(const float4*)(in + i + 4);
  bf16x8 r;
  r[0]=(bf16_t)a.x; r[1]=(bf16_t)a.y; r[2]=(bf16_t)a.z; r[3]=(bf16_t)a.w;
  r[4]=(bf16_t)b.x; r[5]=(bf16_t)b.y; r[6]=(bf16_t)b.z; r[7]=(bf16_t)b.w;
  *(bf16x8*)(out + i) = r;
}

// out[c][r] = bf16(in[r][c]); grid (Cc/32, R/32), 256 threads
__global__ void transpose_cvt(const float* __restrict__ in, bf16_t* __restrict__ out,
                              int R, int Cc) {
  __shared__ float t[32][33];
  const int c0 = blockIdx.x * 32, r0 = blockIdx.y * 32;
  const int tx = threadIdx.x & 31, ty = threadIdx.x >> 5;  // ty 0..7
  #pragma unroll
  for (int k = 0; k < 4; ++k)
    t[ty + k*8][tx] = in[(size_t)(r0 + ty + k*8)*Cc + c0 + tx];
  __syncthreads();
  #pragma unroll
  for (int k = 0; k < 4; ++k)
    out[(size_t)(c0 + ty + k*8)*R + r0 + tx] = (bf16_t)t[tx][ty + k*8];
}

// ---------------------------------------------------------------- GEMM (A row-major MxK, BT row-major NxK)
// MODE 0: Cout = A@B + bias (fp32, stride Ndim)
// MODE 1: qkv scatter (q -> (b,h,n,d); k,v -> transposed (b,h,d,n)), bf16
// 1-D grid with XCD-chunked swizzle; nbx = column blocks.
template<int MODE>
__global__ __launch_bounds__(256, 2)
void gemm_bt(const bf16_t* __restrict__ A, const bf16_t* __restrict__ BT,
             const float* __restrict__ bias, float* __restrict__ Cout,
             bf16_t* __restrict__ qh,
             bf16_t* __restrict__ kthi, bf16_t* __restrict__ vthi,
             int K, int Ndim, int nbx)
{
  // union: staging buffers (16 KB) reused as 128x136 bf16 epilogue tile (34 KB)
  __shared__ __align__(16) char smem[34816];
  bf16_t* As   = (bf16_t*)smem;            // [128][32]
  bf16_t* Bs   = (bf16_t*)(smem + 8192);   // [128][32]
  bf16_t* tile = (bf16_t*)smem;            // [128 cols][pitch 136 rows]

  const int nwg = gridDim.x;
  const int cpx = nwg >> 3;                       // nwg % 8 == 0
  const int bid = blockIdx.x;
  const int swz = (bid & 7) * cpx + (bid >> 3);   // bijective XCD chunking
  const int bx  = swz % nbx;
  const int by  = swz / nbx;

  const int tid  = threadIdx.x;
  const int wave = tid >> 6;
  const int lane = tid & 63;
  const int rowBase = by * 128;
  const int colBase = bx * 128;
  const int wr = (wave >> 1) * 64;
  const int wc = (wave &  1) * 64;
  const int fr = lane & 15;
  const int fo = (lane >> 4) * 8;
  const int e  = tid * 8;
  const int r0t = e >> 5;    // tile row within [128][32]
  const int c0t = e & 31;

  const bf16_t* Ap = A  + (size_t)(rowBase + r0t) * K + c0t;
  const bf16_t* Bp = BT + (size_t)(colBase + r0t) * K + c0t;

  f32x4 acc[4][4] = {{0.f,0.f,0.f,0.f}};

  for (int k0 = 0; k0 < K; k0 += 32) {
    lds_load16(Ap + k0,                 &As[wave*512]);
    lds_load16(Ap + (size_t)64*K + k0,  &As[2048 + wave*512]);
    lds_load16(Bp + k0,                 &Bs[wave*512]);
    lds_load16(Bp + (size_t)64*K + k0,  &Bs[2048 + wave*512]);
    __syncthreads();
    bf16x8 af[4], bfv[4];
    #pragma unroll
    for (int m = 0; m < 4; ++m) af[m]  = *(const bf16x8*)&As[(wr + m*16 + fr)*32 + fo];
    #pragma unroll
    for (int n = 0; n < 4; ++n) bfv[n] = *(const bf16x8*)&Bs[(wc + n*16 + fr)*32 + fo];
    #pragma unroll
    for (int m = 0; m < 4; ++m)
      #pragma unroll
      for (int n = 0; n < 4; ++n)
        acc[m][n] = MFMA16(af[m], bfv[n], acc[m][n]);
    __syncthreads();
  }

  if (MODE == 0) {
    #pragma unroll
    for (int n = 0; n < 4; ++n) {
      const int gc = colBase + wc + n*16 + fr;
      const float bb = bias[gc];
      #pragma unroll
      for (int m = 0; m < 4; ++m) {
        const int gr = rowBase + wr + m*16 + ((lane >> 4) << 2);
        #pragma unroll
        for (int j = 0; j < 4; ++j)
          Cout[(size_t)(gr + j)*Ndim + gc] = acc[m][n][j] + bb;
      }
    }
  } else {
    // ---- stage fragments (bias added, bf16) into transposed LDS tile ----
    // frag (m,n): col c = wc+n*16+fr, rows r0..r0+3 contiguous -> bf16x4 write
    #pragma unroll
    for (int n = 0; n < 4; ++n) {
      const int c  = wc + n*16 + fr;
      const float bb = bias[colBase + c];
      #pragma unroll
      for (int m = 0; m < 4; ++m) {
        const int r0 = wr + m*16 + ((lane >> 4) << 2);
        bf16x4 hv;
        hv[0]=(bf16_t)(acc[m][n][0]+bb); hv[1]=(bf16_t)(acc[m][n][1]+bb);
        hv[2]=(bf16_t)(acc[m][n][2]+bb); hv[3]=(bf16_t)(acc[m][n][3]+bb);
        *(bf16x4*)&tile[c*136 + r0] = hv;
      }
    }
    __syncthreads();
    const int s   = colBase / C_;          // 0=q 1=k 2=v (uniform per block)
    const int b   = rowBase >> 10;
    const int nn0 = rowBase & (N_ - 1);
    if (s == 0) {
      // q: row-major (b,h,n,d). thread t: row r=t>>1, head-half ch=t&1.
      const int r  = tid >> 1, ch = tid & 1;
      const int h  = (colBase >> 6) + ch;
      bf16_t* dst = qh + (((size_t)b*H_ + h)*N_ + nn0 + r)*D_;
      #pragma unroll
      for (int i0 = 0; i0 < 64; i0 += 8) {
        bf16x8 vv;
        #pragma unroll
        for (int i = 0; i < 8; ++i) vv[i] = tile[(ch*64 + i0 + i)*136 + r];
        *(bf16x8*)&dst[i0] = vv;
      }
    } else {
      // k/v: transposed (b,h,d,n). thread t: col c=t>>1, row-half rh=t&1.
      const int c  = tid >> 1, rh = tid & 1;
      const int rem = colBase + c - s*C_;
      const int h = rem >> 6, d = rem & 63;
      bf16_t* dst = (s == 1 ? kthi : vthi)
                    + (((size_t)b*H_ + h)*D_ + d)*N_ + nn0 + rh*64;
      #pragma unroll
      for (int i0 = 0; i0 < 64; i0 += 8)
        *(bf16x8*)&dst[i0] = *(const bf16x8*)&tile[c*136 + rh*64 + i0];
    }
  }
}

// ---------------------------------------------------------------- stage 2: logits + softmax
// attn[bh][d][e] = softmax_e( sum_n kt[d][n]*vt[e][n] / 8 ), kt/vt are (D,N) bf16
__global__ __launch_bounds__(256, 2)
void attn_softmax_k(const bf16_t* __restrict__ kthi, const bf16_t* __restrict__ vthi,
                    bf16_t* __restrict__ attn)
{
  __shared__ float tile[64][65];
  const int bh = blockIdx.x;
  const int tid = threadIdx.x, wave = tid >> 6, lane = tid & 63;
  const int fr = lane & 15, fo = (lane >> 4) * 8;
  const size_t base = (size_t)bh * D_ * N_;
  f32x4 acc[4][4] = {{0.f,0.f,0.f,0.f}};
  const int k0lo = wave * 256;   // split-K across 4 waves
  #pragma unroll 1
  for (int k0 = k0lo; k0 < k0lo + 256; k0 += 32) {
    bf16x8 ah[4], bhv[4];
    #pragma unroll
    for (int m = 0; m < 4; ++m)
      ah[m] = *(const bf16x8*)&kthi[base + (size_t)(m*16 + fr)*N_ + k0 + fo];
    #pragma unroll
    for (int n = 0; n < 4; ++n)
      bhv[n] = *(const bf16x8*)&vthi[base + (size_t)(n*16 + fr)*N_ + k0 + fo];
    #pragma unroll
    for (int m = 0; m < 4; ++m)
      #pragma unroll
      for (int n = 0; n < 4; ++n)
        acc[m][n] = MFMA16(ah[m], bhv[n], acc[m][n]);
  }
  // cross-wave reduce into LDS
  for (int w = 0; w < 4; ++w) {
    if (wave == w) {
      #pragma unroll
      for (int m = 0; m < 4; ++m)
        #pragma unroll
        for (int n = 0; n < 4; ++n) {
          const int row = m*16 + ((lane >> 4) << 2);
          const int col = n*16 + fr;
          #pragma unroll
          for (int j = 0; j < 4; ++j) {
            if (w == 0) tile[row+j][col]  = acc[m][n][j];
            else        tile[row+j][col] += acc[m][n][j];
          }
        }
    }
    __syncthreads();
  }
  // row softmax (scale 1/8), one thread per row
  if (tid < 64) {
    float mx = -3.0e38f;
    #pragma unroll
    for (int c = 0; c < 64; ++c) mx = fmaxf(mx, tile[tid][c]);
    mx *= 0.125f;
    float ssum = 0.f;
    #pragma unroll
    for (int c = 0; c < 64; ++c) {
      const float ev = __expf(tile[tid][c]*0.125f - mx);
      tile[tid][c] = ev;
      ssum += ev;
    }
    const float inv = 1.0f / ssum;
    bf16_t* ao = attn + (size_t)bh * D_ * D_ + tid * D_;
    #pragma unroll
    for (int c = 0; c < 64; ++c) ao[c] = (bf16_t)(tile[tid][c] * inv);
  }
}

// ---------------------------------------------------------------- stage 3: out2 = Q @ attn^T, merge heads
// y2[b][n][h*64+d] = sum_e attn[d][e] * q[n][e]
__global__ __launch_bounds__(256, 2)
void attn_apply(const bf16_t* __restrict__ qh, const bf16_t* __restrict__ attn,
                bf16_t* __restrict__ y2)
{
  const int bh = blockIdx.y;
  const int b = bh / H_, h = bh - b*H_;
  const int tid = threadIdx.x, wave = tid >> 6, lane = tid & 63;
  const int fr = lane & 15, fo = (lane >> 4) * 8;
  const int n0 = blockIdx.x * 256 + wave * 64;
  const bf16_t* qb = qh   + (size_t)bh * N_ * D_;
  const bf16_t* ab = attn + (size_t)bh * D_ * D_;
  f32x4 acc[4][4] = {{0.f,0.f,0.f,0.f}};
  #pragma unroll
  for (int k0 = 0; k0 < 64; k0 += 32) {
    bf16x8 af[4], bfv[4];
    #pragma unroll
    for (int m = 0; m < 4; ++m)
      af[m] = *(const bf16x8*)&qb[(size_t)(n0 + m*16 + fr)*D_ + k0 + fo];
    #pragma unroll
    for (int n = 0; n < 4; ++n)
      bfv[n] = *(const bf16x8*)&ab[(n*16 + fr)*D_ + k0 + fo];
    #pragma unroll
    for (int m = 0; m < 4; ++m)
      #pragma unroll
      for (int n = 0; n < 4; ++n)
        acc[m][n] = MFMA16(af[m], bfv[n], acc[m][n]);
  }
  #pragma unroll
  for (int m = 0; m < 4; ++m) {
    const int nr = n0 + m*16 + ((lane >> 4) << 2);
    #pragma unroll
    for (int n = 0; n < 4; ++n) {
      const int d = n*16 + fr;
      #pragma unroll
      for (int j = 0; j < 4; ++j)
        y2[(size_t)(b*N_ + nr + j)*C_ + h*D_ + d] = (bf16_t)acc[m][n][j];
    }
  }
}

// ---------------------------------------------------------------- launcher
extern "C" void kernel_launch(void* const* d_in, const int* in_sizes, int n_in,
                              void* d_out, int out_size, void* d_ws, size_t ws_size,
                              hipStream_t stream)
{
  (void)in_sizes; (void)n_in; (void)out_size;
  const float* x     = (const float*)d_in[0];
  const float* w_qkv = (const float*)d_in[1];
  const float* b_qkv = (const float*)d_in[2];
  const float* w_out = (const float*)d_in[3];
  const float* b_out = (const float*)d_in[4];
  float* out = (float*)d_out;

  const size_t sz_xb   = (size_t)M_*C_*2;        // 50.3 MB
  const size_t sz_wq   = (size_t)TC_*C_*2;       //  3.5 MB
  const size_t sz_wo   = (size_t)C_*C_*2;        //  1.2 MB
  const size_t sz_qh   = (size_t)B_*H_*N_*D_*2;  // 50.3 MB
  const size_t sz_kv   = (size_t)B_*H_*D_*N_*2;  // 50.3 MB each
  const size_t sz_attn = (size_t)B_*H_*D_*D_*2;  //  3.1 MB

  char* p = (char*)d_ws;
  bf16_t* xb    = (bf16_t*)p; p += sz_xb;
  bf16_t* wqkvT = (bf16_t*)p; p += sz_wq;
  bf16_t* woutT = (bf16_t*)p; p += sz_wo;
  bf16_t* qh    = (bf16_t*)p; p += sz_qh;
  bf16_t* kthi  = (bf16_t*)p; p += sz_kv;
  bf16_t* vthi  = (bf16_t*)p; p += sz_kv;
  bf16_t* attn  = (bf16_t*)p; p += sz_attn;
  const size_t base_need = (size_t)(p - (char*)d_ws);
  bf16_t* y2 = xb;   // xb is dead after GEMM1; reuse for merged attention output

  if (ws_size < base_need) return;   // leaves poison -> distinctive failure

  cvt_bf16<<<dim3((M_*C_)/2048), 256, 0, stream>>>(x, xb, M_*C_);
  transpose_cvt<<<dim3(TC_/32, C_/32), 256, 0, stream>>>(w_qkv, wqkvT, C_, TC_);
  transpose_cvt<<<dim3(C_/32,  C_/32), 256, 0, stream>>>(w_out, woutT, C_, C_);

  // GEMM1: qkv projection with scatter epilogue. grid = 18 x 256 = 4608 (8 | 4608)
  gemm_bt<1><<<dim3((TC_/128)*(M_/128)), 256, 0, stream>>>(
      xb, wqkvT, b_qkv, nullptr, qh, kthi, vthi, C_, 0, TC_/128);

  attn_softmax_k<<<dim3(B_*H_), 256, 0, stream>>>(kthi, vthi, attn);

  attn_apply<<<dim3(N_/256, B_*H_), 256, 0, stream>>>(qh, attn, y2);

  // GEMM2: out projection. grid = 6 x 256 = 1536 (8 | 1536)
  gemm_bt<0><<<dim3((C_/128)*(M_/128)), 256, 0, stream>>>(
      y2, woutT, b_out, out, nullptr, nullptr, nullptr, C_, C_, C_/128);
}